// Round 1
// baseline (795.265 us; speedup 1.0000x reference)
//
#include <hip/hip_runtime.h>
#include <math.h>

namespace {

constexpr int B_ = 2;
constexpr int S_ = 4;
constexpr int Y_ = 4;

// One thread per output element v[b, c*Y+y, m].
// v[b,i,m] = max_{s} ( valid(bs,n) ? bilinear(feat[bs,c], coords[bs,n]) : 0 )
// with bs = b*S+s, n = y*M+m.  Exact reference semantics (floor->int->clamp).
__global__ void sample_max_kernel(const float* __restrict__ feat,   // (B*S, C, W, W)
                                  const float* __restrict__ coords, // (B*S, Y*M, 2)
                                  float* __restrict__ vout,         // (B, C*Y, M)
                                  int C, int Wd, int M)
{
    long idx = (long)blockIdx.x * blockDim.x + threadIdx.x;
    long total = (long)B_ * C * Y_ * M;
    if (idx >= total) return;
    int m = (int)(idx % M);
    long t = idx / M;
    int y = (int)(t % Y_);
    t /= Y_;
    int c = (int)(t % C);
    int b = (int)(t / C);
    int n = y * M + m;

    float best = -3.4e38f;
    #pragma unroll
    for (int s = 0; s < S_; ++s) {
        int bs = b * S_ + s;
        float2 g = ((const float2*)coords)[(long)bs * (Y_ * M) + n];
        float ix = (g.x + 1.f) * 0.5f * (float)(Wd - 1);
        float iy = (g.y + 1.f) * 0.5f * (float)(Wd - 1);
        float x0f = floorf(ix);
        float y0f = floorf(iy);
        float wx = ix - x0f;
        float wy = iy - y0f;
        int x0 = (int)x0f; x0 = min(max(x0, 0), Wd - 1);
        int x1 = min(x0 + 1, Wd - 1);
        int y0 = (int)y0f; y0 = min(max(y0, 0), Wd - 1);
        int y1 = min(y0 + 1, Wd - 1);
        const float* fp = feat + ((long)bs * C + c) * (Wd * Wd);
        float v00 = fp[y0 * Wd + x0];
        float v01 = fp[y0 * Wd + x1];
        float v10 = fp[y1 * Wd + x0];
        float v11 = fp[y1 * Wd + x1];
        float samp = v00 * (1.f - wx) * (1.f - wy)
                   + v01 * wx        * (1.f - wy)
                   + v10 * (1.f - wx) * wy
                   + v11 * wx        * wy;
        bool valid = (g.x >= -1.f) && (g.x <= 1.f) && (g.y >= -1.f) && (g.y <= 1.f);
        float val = valid ? samp : 0.f;
        best = fmaxf(best, val);
    }
    vout[((long)b * (C * Y_) + (c * Y_ + y)) * M + m] = best;
}

// out[b,o,m] = silu( sum_i V[b,i,m] * Wt[o,i] + bias[o] )
// Tiled fp32 GEMM: 64(o) x 64(m) tile, K-step 16, 256 threads, 4x4 per thread.
__global__ __launch_bounds__(256) void gemm_bias_silu(
    const float* __restrict__ V,    // (B, K, M)
    const float* __restrict__ Wt,   // (N, K)
    const float* __restrict__ bias, // (N)
    float* __restrict__ out,        // (B, N, M)
    int N, int K, int M)
{
    __shared__ float Ws[64][17];   // [o'][k'] +1 pad
    __shared__ float Vs[16][68];   // [k'][m'] +4 pad

    int b = blockIdx.z;
    int mBase = blockIdx.x * 64;
    int oBase = blockIdx.y * 64;
    int tid = threadIdx.x;
    int tx = tid & 15;    // m-group
    int ty = tid >> 4;    // o-group

    float acc[4][4] = {{0.f, 0.f, 0.f, 0.f}, {0.f, 0.f, 0.f, 0.f},
                       {0.f, 0.f, 0.f, 0.f}, {0.f, 0.f, 0.f, 0.f}};

    const float* Vb = V + (long)b * K * M;
    int wrow = tid >> 2, wcol = (tid & 3) << 2;    // 64x16 W tile, float4 each
    int vrow = tid >> 4, vcol = (tid & 15) << 2;   // 16x64 V tile, float4 each

    for (int k0 = 0; k0 < K; k0 += 16) {
        float4 wf = *(const float4*)(Wt + (long)(oBase + wrow) * K + k0 + wcol);
        float4 vf = *(const float4*)(Vb + (long)(k0 + vrow) * M + mBase + vcol);
        Ws[wrow][wcol + 0] = wf.x; Ws[wrow][wcol + 1] = wf.y;
        Ws[wrow][wcol + 2] = wf.z; Ws[wrow][wcol + 3] = wf.w;
        Vs[vrow][vcol + 0] = vf.x; Vs[vrow][vcol + 1] = vf.y;
        Vs[vrow][vcol + 2] = vf.z; Vs[vrow][vcol + 3] = vf.w;
        __syncthreads();
        #pragma unroll
        for (int kk = 0; kk < 16; ++kk) {
            float wv[4], vv[4];
            #pragma unroll
            for (int i = 0; i < 4; ++i) wv[i] = Ws[ty * 4 + i][kk];
            #pragma unroll
            for (int j = 0; j < 4; ++j) vv[j] = Vs[kk][tx * 4 + j];
            #pragma unroll
            for (int i = 0; i < 4; ++i)
                #pragma unroll
                for (int j = 0; j < 4; ++j)
                    acc[i][j] += wv[i] * vv[j];
        }
        __syncthreads();
    }

    #pragma unroll
    for (int i = 0; i < 4; ++i) {
        int o = oBase + ty * 4 + i;
        float bi = bias[o];
        float4 r;
        float vtmp[4];
        #pragma unroll
        for (int j = 0; j < 4; ++j) {
            float x = acc[i][j] + bi;
            vtmp[j] = x / (1.f + expf(-x));   // silu
        }
        r.x = vtmp[0]; r.y = vtmp[1]; r.z = vtmp[2]; r.w = vtmp[3];
        *(float4*)(out + ((long)b * N + o) * M + mBase + tx * 4) = r;
    }
}

// valid_vox_mask[b,n] = any_s valid(coords_s2[b*S+s, n])
__global__ void mask_kernel(const float* __restrict__ coords, // (B*S, Ntot, 2)
                            float* __restrict__ out,          // (B, Ntot)
                            int Ntot)
{
    int idx = blockIdx.x * blockDim.x + threadIdx.x;
    if (idx >= B_ * Ntot) return;
    int n = idx % Ntot;
    int b = idx / Ntot;
    float best = 0.f;
    #pragma unroll
    for (int s = 0; s < S_; ++s) {
        float2 g = ((const float2*)coords)[(long)(b * S_ + s) * Ntot + n];
        bool valid = (g.x >= -1.f) && (g.x <= 1.f) && (g.y >= -1.f) && (g.y <= 1.f);
        if (valid) best = 1.f;
    }
    out[idx] = best;
}

} // namespace

extern "C" void kernel_launch(void* const* d_in, const int* in_sizes, int n_in,
                              void* d_out, int out_size, void* d_ws, size_t ws_size,
                              hipStream_t stream)
{
    const float* x3 = (const float*)d_in[0];
    const float* x4 = (const float*)d_in[1];
    const float* x5 = (const float*)d_in[2];
    const float* c2 = (const float*)d_in[3];
    const float* c4 = (const float*)d_in[4];
    const float* c8 = (const float*)d_in[5];
    const float* w2 = (const float*)d_in[6];
    const float* b2 = (const float*)d_in[7];
    const float* w4 = (const float*)d_in[8];
    const float* b4 = (const float*)d_in[9];
    const float* w8 = (const float*)d_in[10];
    const float* b8 = (const float*)d_in[11];

    float* out  = (float*)d_out;
    float* bev2 = out;
    float* bev4 = bev2 + (long)2 * 256 * 64 * 64;
    float* bev8 = bev4 + (long)2 * 512 * 32 * 32;
    float* mask = bev8 + (long)2 * 1024 * 16 * 16;

    float* v = (float*)d_ws;  // reused per scale; max = 2*1024*4096*4B = 32 MB

    // ---- scale 2: C=256, W=64, M=4096, K=1024, N=256 ----
    {
        long total = 2L * 256 * Y_ * 4096;
        sample_max_kernel<<<dim3((unsigned)((total + 255) / 256)), 256, 0, stream>>>(
            x3, c2, v, 256, 64, 4096);
        gemm_bias_silu<<<dim3(4096 / 64, 256 / 64, 2), 256, 0, stream>>>(
            v, w2, b2, bev2, 256, 1024, 4096);
    }
    // ---- scale 4: C=512, W=32, M=1024, K=2048, N=512 ----
    {
        long total = 2L * 512 * Y_ * 1024;
        sample_max_kernel<<<dim3((unsigned)((total + 255) / 256)), 256, 0, stream>>>(
            x4, c4, v, 512, 32, 1024);
        gemm_bias_silu<<<dim3(1024 / 64, 512 / 64, 2), 256, 0, stream>>>(
            v, w4, b4, bev4, 512, 2048, 1024);
    }
    // ---- scale 8: C=1024, W=16, M=256, K=4096, N=1024 ----
    {
        long total = 2L * 1024 * Y_ * 256;
        sample_max_kernel<<<dim3((unsigned)((total + 255) / 256)), 256, 0, stream>>>(
            x5, c8, v, 1024, 16, 256);
        gemm_bias_silu<<<dim3(256 / 64, 1024 / 64, 2), 256, 0, stream>>>(
            v, w8, b8, bev8, 1024, 4096, 256);
    }
    // ---- validity mask (scale-2 coords only) ----
    mask_kernel<<<dim3((2 * 16384 + 255) / 256), 256, 0, stream>>>(c2, mask, 16384);
}

// Round 2
// 672.241 us; speedup vs baseline: 1.1830x; 1.1830x over previous
//
#include <hip/hip_runtime.h>
#include <hip/hip_bf16.h>
#include <math.h>

namespace {

constexpr int B_ = 2;
constexpr int S_ = 4;
constexpr int Y_ = 4;

typedef short short8 __attribute__((ext_vector_type(8)));
typedef float floatx4 __attribute__((ext_vector_type(4)));

__device__ __forceinline__ unsigned short f2bf(float x) {
    union { float f; unsigned u; } a; a.f = x;
    unsigned r = a.u + 0x7fff + ((a.u >> 16) & 1);   // round-to-nearest-even
    return (unsigned short)(r >> 16);
}

// float -> bf16 bulk convert (n multiple of 1024, grid = n/1024 blocks of 256)
__global__ void cvt_bf16(const float* __restrict__ in, unsigned short* __restrict__ out) {
    long idx = ((long)blockIdx.x * 256 + threadIdx.x) * 4;
    float4 v = *reinterpret_cast<const float4*>(in + idx);
    ushort4 u;
    u.x = f2bf(v.x); u.y = f2bf(v.y); u.z = f2bf(v.z); u.w = f2bf(v.w);
    *reinterpret_cast<ushort4*>(out + idx) = u;
}

// One thread per (b, m, i) with i = c*Y + y fastest; writes V transposed as
// (B, M, K) bf16, k-contiguous (coalesced).  Exact reference bilinear+valid+max.
__global__ void sample_max_t(const float* __restrict__ feat,   // (B*S, C, W, W)
                             const float* __restrict__ coords, // (B*S, Y*M, 2)
                             unsigned short* __restrict__ vout,// (B, M, K) bf16
                             int Wd, int M, int logK, int logM)
{
    int K = 1 << logK;
    long idx = (long)blockIdx.x * 256 + threadIdx.x;  // grid sized exactly
    int i = (int)idx & (K - 1);
    int m = (int)(idx >> logK) & (M - 1);
    int b = (int)(idx >> (logK + logM));
    int c = i >> 2;
    int y = i & 3;
    int n = y * M + m;

    float best = -3.4e38f;
    #pragma unroll
    for (int s = 0; s < S_; ++s) {
        int bs = b * S_ + s;
        float2 g = ((const float2*)coords)[(long)bs * (Y_ * M) + n];
        float ix = (g.x + 1.f) * 0.5f * (float)(Wd - 1);
        float iy = (g.y + 1.f) * 0.5f * (float)(Wd - 1);
        float x0f = floorf(ix);
        float y0f = floorf(iy);
        float wx = ix - x0f;
        float wy = iy - y0f;
        int x0 = (int)x0f; x0 = min(max(x0, 0), Wd - 1);
        int x1 = min(x0 + 1, Wd - 1);
        int y0 = (int)y0f; y0 = min(max(y0, 0), Wd - 1);
        int y1 = min(y0 + 1, Wd - 1);
        const float* fp = feat + ((long)bs * (K >> 2) + c) * (Wd * Wd);
        float v00 = fp[y0 * Wd + x0];
        float v01 = fp[y0 * Wd + x1];
        float v10 = fp[y1 * Wd + x0];
        float v11 = fp[y1 * Wd + x1];
        float samp = v00 * (1.f - wx) * (1.f - wy)
                   + v01 * wx        * (1.f - wy)
                   + v10 * (1.f - wx) * wy
                   + v11 * wx        * wy;
        bool valid = (g.x >= -1.f) && (g.x <= 1.f) && (g.y >= -1.f) && (g.y <= 1.f);
        float val = valid ? samp : 0.f;
        best = fmaxf(best, val);
    }
    vout[idx] = f2bf(best);
}

// out[b,o,m] = silu( sum_k W[o,k] * V[b,m,k] + bias[o] )
// MFMA bf16 GEMM: 64(o) x 64(m) tile, BK=64, 256 threads = 4 waves,
// each wave a 32x32 quadrant = 2x2 tiles of 16x16x32.
// N, M multiples of 64; K multiple of 64.
__global__ __launch_bounds__(256) void gemm_mfma_silu(
    const unsigned short* __restrict__ Wb,  // (N, K) bf16
    const unsigned short* __restrict__ Vb,  // (B, M, K) bf16
    const float* __restrict__ bias,         // (N)
    float* __restrict__ out,                // (B, N, M)
    int N, int K, int M)
{
    // rows padded to 72 bf16 (144 B): bank stride 4 -> 2-way (free)
    __shared__ __align__(16) unsigned short As[64 * 72];  // W tile [o][k]
    __shared__ __align__(16) unsigned short Bs[64 * 72];  // V tile [m][k]

    const int b = blockIdx.z;
    const int mBase = blockIdx.x * 64;
    const int oBase = blockIdx.y * 64;
    const int tid = threadIdx.x;
    const int lane = tid & 63;
    const int wave = tid >> 6;
    const int wo = (wave >> 1) * 32;
    const int wm = (wave & 1) * 32;
    const int quad = lane >> 4;
    const int lr = lane & 15;

    floatx4 acc[2][2] = {};

    const unsigned short* Wp = Wb + (size_t)oBase * K;
    const unsigned short* Vp = Vb + ((size_t)b * M + mBase) * K;

    for (int k0 = 0; k0 < K; k0 += 64) {
        #pragma unroll
        for (int p = 0; p < 2; ++p) {
            int idx = tid + p * 256;
            int row = idx >> 3;          // 0..63
            int kc = (idx & 7) * 8;      // 0..56
            float4 wv = *reinterpret_cast<const float4*>(Wp + (size_t)row * K + k0 + kc);
            float4 vv = *reinterpret_cast<const float4*>(Vp + (size_t)row * K + k0 + kc);
            *reinterpret_cast<float4*>(&As[row * 72 + kc]) = wv;
            *reinterpret_cast<float4*>(&Bs[row * 72 + kc]) = vv;
        }
        __syncthreads();
        #pragma unroll
        for (int ks = 0; ks < 64; ks += 32) {
            short8 af[2], bfr[2];
            #pragma unroll
            for (int i = 0; i < 2; ++i)
                af[i] = *reinterpret_cast<const short8*>(&As[(wo + i * 16 + lr) * 72 + ks + quad * 8]);
            #pragma unroll
            for (int j = 0; j < 2; ++j)
                bfr[j] = *reinterpret_cast<const short8*>(&Bs[(wm + j * 16 + lr) * 72 + ks + quad * 8]);
            #pragma unroll
            for (int i = 0; i < 2; ++i)
                #pragma unroll
                for (int j = 0; j < 2; ++j)
                    acc[i][j] = __builtin_amdgcn_mfma_f32_16x16x32_bf16(af[i], bfr[j], acc[i][j], 0, 0, 0);
        }
        __syncthreads();
    }

    #pragma unroll
    for (int i = 0; i < 2; ++i) {
        #pragma unroll
        for (int r = 0; r < 4; ++r) {
            int o = oBase + wo + i * 16 + quad * 4 + r;
            float bi = bias[o];
            #pragma unroll
            for (int j = 0; j < 2; ++j) {
                int m = mBase + wm + j * 16 + lr;
                float x = acc[i][j][r] + bi;
                out[((size_t)b * N + o) * M + m] = x / (1.f + __expf(-x));
            }
        }
    }
}

// valid_vox_mask[b,n] = any_s valid(coords_s2[b*S+s, n])
__global__ void mask_kernel(const float* __restrict__ coords, // (B*S, Ntot, 2)
                            float* __restrict__ out,          // (B, Ntot)
                            int Ntot)
{
    int idx = blockIdx.x * blockDim.x + threadIdx.x;
    if (idx >= B_ * Ntot) return;
    int n = idx % Ntot;
    int b = idx / Ntot;
    float best = 0.f;
    #pragma unroll
    for (int s = 0; s < S_; ++s) {
        float2 g = ((const float2*)coords)[(long)(b * S_ + s) * Ntot + n];
        bool valid = (g.x >= -1.f) && (g.x <= 1.f) && (g.y >= -1.f) && (g.y <= 1.f);
        if (valid) best = 1.f;
    }
    out[idx] = best;
}

} // namespace

extern "C" void kernel_launch(void* const* d_in, const int* in_sizes, int n_in,
                              void* d_out, int out_size, void* d_ws, size_t ws_size,
                              hipStream_t stream)
{
    const float* x3 = (const float*)d_in[0];
    const float* x4 = (const float*)d_in[1];
    const float* x5 = (const float*)d_in[2];
    const float* c2 = (const float*)d_in[3];
    const float* c4 = (const float*)d_in[4];
    const float* c8 = (const float*)d_in[5];
    const float* w2 = (const float*)d_in[6];
    const float* b2 = (const float*)d_in[7];
    const float* w4 = (const float*)d_in[8];
    const float* b4 = (const float*)d_in[9];
    const float* w8 = (const float*)d_in[10];
    const float* b8 = (const float*)d_in[11];

    float* out  = (float*)d_out;
    float* bev2 = out;
    float* bev4 = bev2 + (long)2 * 256 * 64 * 64;
    float* bev8 = bev4 + (long)2 * 512 * 32 * 32;
    float* mask = bev8 + (long)2 * 1024 * 16 * 16;

    char* ws = (char*)d_ws;
    unsigned short* vbf  = (unsigned short*)ws;                       // <= 16 MB
    unsigned short* w2bf = (unsigned short*)(ws + (16L << 20));       // 0.5 MB
    unsigned short* w4bf = (unsigned short*)(ws + (16L << 20) + (1L << 19));
    unsigned short* w8bf = (unsigned short*)(ws + (16L << 20) + (1L << 19) + (2L << 20));

    // weight conversions (float -> bf16); sizes are multiples of 1024
    cvt_bf16<<<dim3(256 * 1024 / 1024), 256, 0, stream>>>(w2, w2bf);
    cvt_bf16<<<dim3(512 * 2048 / 1024), 256, 0, stream>>>(w4, w4bf);
    cvt_bf16<<<dim3(1024 * 4096 / 1024), 256, 0, stream>>>(w8, w8bf);

    // ---- scale 2: C=256, W=64, M=4096, K=1024, N=256 ----
    {
        long total = 2L * 4096 * 1024;   // B*M*K
        sample_max_t<<<dim3((unsigned)(total / 256)), 256, 0, stream>>>(
            x3, c2, vbf, 64, 4096, 10, 12);
        gemm_mfma_silu<<<dim3(4096 / 64, 256 / 64, 2), 256, 0, stream>>>(
            w2bf, vbf, b2, bev2, 256, 1024, 4096);
    }
    // ---- scale 4: C=512, W=32, M=1024, K=2048, N=512 ----
    {
        long total = 2L * 1024 * 2048;
        sample_max_t<<<dim3((unsigned)(total / 256)), 256, 0, stream>>>(
            x4, c4, vbf, 32, 1024, 11, 10);
        gemm_mfma_silu<<<dim3(1024 / 64, 512 / 64, 2), 256, 0, stream>>>(
            w4bf, vbf, b4, bev4, 512, 2048, 1024);
    }
    // ---- scale 8: C=1024, W=16, M=256, K=4096, N=1024 ----
    {
        long total = 2L * 256 * 4096;
        sample_max_t<<<dim3((unsigned)(total / 256)), 256, 0, stream>>>(
            x5, c8, vbf, 16, 256, 12, 8);
        gemm_mfma_silu<<<dim3(256 / 64, 1024 / 64, 2), 256, 0, stream>>>(
            w8bf, vbf, b8, bev8, 1024, 4096, 256);
    }
    // ---- validity mask (scale-2 coords only) ----
    mask_kernel<<<dim3((2 * 16384 + 255) / 256), 256, 0, stream>>>(c2, mask, 16384);
}

// Round 3
// 347.899 us; speedup vs baseline: 2.2859x; 1.9323x over previous
//
#include <hip/hip_runtime.h>
#include <hip/hip_bf16.h>
#include <math.h>

namespace {

constexpr int B_ = 2;
constexpr int S_ = 4;
constexpr int Y_ = 4;

typedef short short8 __attribute__((ext_vector_type(8)));
typedef float floatx4 __attribute__((ext_vector_type(4)));

__device__ __forceinline__ unsigned short f2bf(float x) {
    union { float f; unsigned u; } a; a.f = x;
    unsigned r = a.u + 0x7fff + ((a.u >> 16) & 1);   // round-to-nearest-even
    return (unsigned short)(r >> 16);
}
__device__ __forceinline__ float bf2f(unsigned short h) {
    union { unsigned u; float f; } a; a.u = ((unsigned)h) << 16;
    return a.f;
}

// float -> bf16 bulk convert (n multiple of 1024, grid = n/1024 blocks of 256)
__global__ void cvt_bf16(const float* __restrict__ in, unsigned short* __restrict__ out) {
    long idx = ((long)blockIdx.x * 256 + threadIdx.x) * 4;
    float4 v = *reinterpret_cast<const float4*>(in + idx);
    ushort4 u;
    u.x = f2bf(v.x); u.y = f2bf(v.y); u.z = f2bf(v.z); u.w = f2bf(v.w);
    *reinterpret_cast<ushort4*>(out + idx) = u;
}

// feat (BS, C, P) f32 -> featT (BS, P, C) bf16.  32x32 LDS tiles. C,P % 32 == 0.
__global__ __launch_bounds__(256) void transpose_bf16(
    const float* __restrict__ in, unsigned short* __restrict__ out, int C, int P)
{
    __shared__ float tile[32][33];
    int bs = blockIdx.z;
    int pBase = blockIdx.x * 32;
    int cBase = blockIdx.y * 32;
    int tx = threadIdx.x & 31;
    int ty = threadIdx.x >> 5;   // 0..7
    const float* ip = in + ((size_t)bs * C + cBase) * P + pBase;
    #pragma unroll
    for (int r = 0; r < 32; r += 8)
        tile[ty + r][tx] = ip[(size_t)(ty + r) * P + tx];
    __syncthreads();
    unsigned short* op = out + ((size_t)bs * P + pBase) * C + cBase;
    #pragma unroll
    for (int r = 0; r < 32; r += 8)
        op[(size_t)(ty + r) * C + tx] = f2bf(tile[tx][ty + r]);
}

// One WAVE per (b, m, c-chunk of 64).  Corner positions/weights are wave-uniform;
// corner loads are coalesced over channels (featT is channels-last bf16).
// Each lane produces best[y=0..3] for its channel and writes ushort4 (k=c*4+y).
__global__ __launch_bounds__(256) void sample_max_v2(
    const unsigned short* __restrict__ featT, // (BS, P, C) bf16
    const float* __restrict__ coords,         // (BS, Y*M, 2)
    unsigned short* __restrict__ vout,        // (B, M, K=4C) bf16
    int Wd, int M, int C, int logM, int logCc)
{
    int wid = (int)((blockIdx.x * 256 + threadIdx.x) >> 6);
    int lane = threadIdx.x & 63;
    int nc1 = (1 << logCc) - 1;
    int cchunk = wid & nc1;
    int m = (wid >> logCc) & (M - 1);
    int b = wid >> (logCc + logM);
    int c = cchunk * 64 + lane;
    int P = Wd * Wd;

    float best[4];
    #pragma unroll
    for (int y = 0; y < 4; ++y) {
        float bst = -3.4e38f;
        bool anyinv = false;
        #pragma unroll
        for (int s = 0; s < 4; ++s) {
            int bs = b * S_ + s;
            float2 g = ((const float2*)coords)[((size_t)bs << (logM + 2)) + ((size_t)y << logM) + m];
            bool valid = (g.x >= -1.f) && (g.x <= 1.f) && (g.y >= -1.f) && (g.y <= 1.f);
            if (!valid) { anyinv = true; continue; }
            float ix = (g.x + 1.f) * 0.5f * (float)(Wd - 1);
            float iy = (g.y + 1.f) * 0.5f * (float)(Wd - 1);
            float x0f = floorf(ix), y0f = floorf(iy);
            float wx = ix - x0f, wy = iy - y0f;
            int x0 = min(max((int)x0f, 0), Wd - 1);
            int x1 = min(x0 + 1, Wd - 1);
            int y0 = min(max((int)y0f, 0), Wd - 1);
            int y1 = min(y0 + 1, Wd - 1);
            const unsigned short* fp = featT + (size_t)bs * P * C + c;
            float v00 = bf2f(fp[(y0 * Wd + x0) * C]);
            float v01 = bf2f(fp[(y0 * Wd + x1) * C]);
            float v10 = bf2f(fp[(y1 * Wd + x0) * C]);
            float v11 = bf2f(fp[(y1 * Wd + x1) * C]);
            float samp = v00 * (1.f - wx) * (1.f - wy)
                       + v01 * wx        * (1.f - wy)
                       + v10 * (1.f - wx) * wy
                       + v11 * wx        * wy;
            bst = fmaxf(bst, samp);
        }
        if (anyinv) bst = fmaxf(bst, 0.f);
        best[y] = bst;
    }
    ushort4 o;
    o.x = f2bf(best[0]); o.y = f2bf(best[1]);
    o.z = f2bf(best[2]); o.w = f2bf(best[3]);
    *reinterpret_cast<ushort4*>(vout + (((size_t)b << logM) + m) * (C * 4) + c * 4) = o;
}

// out[b,o,m] = silu( sum_k W[o,k] * V[b,m,k] + bias[o] )
// MFMA bf16 GEMM: 64(o) x 64(m) tile, BK=64, 256 threads = 4 waves,
// each wave a 32x32 quadrant = 2x2 tiles of 16x16x32.
__global__ __launch_bounds__(256) void gemm_mfma_silu(
    const unsigned short* __restrict__ Wb,  // (N, K) bf16
    const unsigned short* __restrict__ Vb,  // (B, M, K) bf16
    const float* __restrict__ bias,         // (N)
    float* __restrict__ out,                // (B, N, M)
    int N, int K, int M)
{
    __shared__ __align__(16) unsigned short As[64 * 72];  // W tile [o][k]
    __shared__ __align__(16) unsigned short Bs[64 * 72];  // V tile [m][k]

    const int b = blockIdx.z;
    const int mBase = blockIdx.x * 64;
    const int oBase = blockIdx.y * 64;
    const int tid = threadIdx.x;
    const int lane = tid & 63;
    const int wave = tid >> 6;
    const int wo = (wave >> 1) * 32;
    const int wm = (wave & 1) * 32;
    const int quad = lane >> 4;
    const int lr = lane & 15;

    floatx4 acc[2][2] = {};

    const unsigned short* Wp = Wb + (size_t)oBase * K;
    const unsigned short* Vp = Vb + ((size_t)b * M + mBase) * K;

    for (int k0 = 0; k0 < K; k0 += 64) {
        #pragma unroll
        for (int p = 0; p < 2; ++p) {
            int idx = tid + p * 256;
            int row = idx >> 3;          // 0..63
            int kc = (idx & 7) * 8;      // 0..56
            float4 wv = *reinterpret_cast<const float4*>(Wp + (size_t)row * K + k0 + kc);
            float4 vv = *reinterpret_cast<const float4*>(Vp + (size_t)row * K + k0 + kc);
            *reinterpret_cast<float4*>(&As[row * 72 + kc]) = wv;
            *reinterpret_cast<float4*>(&Bs[row * 72 + kc]) = vv;
        }
        __syncthreads();
        #pragma unroll
        for (int ks = 0; ks < 64; ks += 32) {
            short8 af[2], bfr[2];
            #pragma unroll
            for (int i = 0; i < 2; ++i)
                af[i] = *reinterpret_cast<const short8*>(&As[(wo + i * 16 + lr) * 72 + ks + quad * 8]);
            #pragma unroll
            for (int j = 0; j < 2; ++j)
                bfr[j] = *reinterpret_cast<const short8*>(&Bs[(wm + j * 16 + lr) * 72 + ks + quad * 8]);
            #pragma unroll
            for (int i = 0; i < 2; ++i)
                #pragma unroll
                for (int j = 0; j < 2; ++j)
                    acc[i][j] = __builtin_amdgcn_mfma_f32_16x16x32_bf16(af[i], bfr[j], acc[i][j], 0, 0, 0);
        }
        __syncthreads();
    }

    #pragma unroll
    for (int i = 0; i < 2; ++i) {
        #pragma unroll
        for (int r = 0; r < 4; ++r) {
            int o = oBase + wo + i * 16 + quad * 4 + r;
            float bi = bias[o];
            #pragma unroll
            for (int j = 0; j < 2; ++j) {
                int m = mBase + wm + j * 16 + lr;
                float x = acc[i][j][r] + bi;
                out[((size_t)b * N + o) * M + m] = x / (1.f + __expf(-x));
            }
        }
    }
}

// valid_vox_mask[b,n] = any_s valid(coords_s2[b*S+s, n])
__global__ void mask_kernel(const float* __restrict__ coords, // (B*S, Ntot, 2)
                            float* __restrict__ out,          // (B, Ntot)
                            int Ntot)
{
    int idx = blockIdx.x * blockDim.x + threadIdx.x;
    if (idx >= B_ * Ntot) return;
    int n = idx % Ntot;
    int b = idx / Ntot;
    float best = 0.f;
    #pragma unroll
    for (int s = 0; s < S_; ++s) {
        float2 g = ((const float2*)coords)[(long)(b * S_ + s) * Ntot + n];
        bool valid = (g.x >= -1.f) && (g.x <= 1.f) && (g.y >= -1.f) && (g.y <= 1.f);
        if (valid) best = 1.f;
    }
    out[idx] = best;
}

} // namespace

extern "C" void kernel_launch(void* const* d_in, const int* in_sizes, int n_in,
                              void* d_out, int out_size, void* d_ws, size_t ws_size,
                              hipStream_t stream)
{
    const float* x3 = (const float*)d_in[0];
    const float* x4 = (const float*)d_in[1];
    const float* x5 = (const float*)d_in[2];
    const float* c2 = (const float*)d_in[3];
    const float* c4 = (const float*)d_in[4];
    const float* c8 = (const float*)d_in[5];
    const float* w2 = (const float*)d_in[6];
    const float* b2 = (const float*)d_in[7];
    const float* w4 = (const float*)d_in[8];
    const float* b4 = (const float*)d_in[9];
    const float* w8 = (const float*)d_in[10];
    const float* b8 = (const float*)d_in[11];

    float* out  = (float*)d_out;
    float* bev2 = out;
    float* bev4 = bev2 + (long)2 * 256 * 64 * 64;
    float* bev8 = bev4 + (long)2 * 512 * 32 * 32;
    float* mask = bev8 + (long)2 * 1024 * 16 * 16;

    // ws layout (total exactly 32 MB, proven available in round 1):
    //   V region:  ws[0 .. 16 MB)   — sampled V (B, M, K) bf16
    //   F region:  ws[16 .. 32 MB)  — featT for current scale, then bf16 weights
    char* ws = (char*)d_ws;
    unsigned short* vbf = (unsigned short*)ws;
    char* F = ws + (16L << 20);

    // ================= scale 2: C=256, W=64, P=4096, M=4096, K=1024, N=256 =====
    {
        unsigned short* featT = (unsigned short*)F;          // 16 MB
        transpose_bf16<<<dim3(4096 / 32, 256 / 32, 8), 256, 0, stream>>>(x3, featT, 256, 4096);
        // waves = B*M*(C/64) = 2*4096*4 = 32768 -> 8192 blocks
        sample_max_v2<<<dim3(8192), 256, 0, stream>>>(featT, c2, vbf, 64, 4096, 256, 12, 2);
        unsigned short* w2bf = (unsigned short*)F;           // featT dead now; 0.5 MB
        cvt_bf16<<<dim3(256 * 1024 / 1024), 256, 0, stream>>>(w2, w2bf);
        gemm_mfma_silu<<<dim3(4096 / 64, 256 / 64, 2), 256, 0, stream>>>(
            w2bf, vbf, b2, bev2, 256, 1024, 4096);
    }
    // ================= scale 4: C=512, W=32, P=1024, M=1024, K=2048, N=512 =====
    {
        unsigned short* featT = (unsigned short*)F;          // 8 MB
        unsigned short* w4bf  = (unsigned short*)(F + (8L << 20));  // 2 MB
        cvt_bf16<<<dim3(512 * 2048 / 1024), 256, 0, stream>>>(w4, w4bf);
        transpose_bf16<<<dim3(1024 / 32, 512 / 32, 8), 256, 0, stream>>>(x4, featT, 512, 1024);
        // waves = 2*1024*8 = 16384 -> 4096 blocks
        sample_max_v2<<<dim3(4096), 256, 0, stream>>>(featT, c4, vbf, 32, 1024, 512, 10, 3);
        gemm_mfma_silu<<<dim3(1024 / 64, 512 / 64, 2), 256, 0, stream>>>(
            w4bf, vbf, b4, bev4, 512, 2048, 1024);
    }
    // ================= scale 8: C=1024, W=16, P=256, M=256, K=4096, N=1024 =====
    {
        unsigned short* featT = (unsigned short*)F;          // 4 MB
        unsigned short* w8bf  = (unsigned short*)(F + (4L << 20));  // 8 MB
        cvt_bf16<<<dim3(1024 * 4096 / 1024), 256, 0, stream>>>(w8, w8bf);
        transpose_bf16<<<dim3(256 / 32, 1024 / 32, 8), 256, 0, stream>>>(x5, featT, 1024, 256);
        // waves = 2*256*16 = 8192 -> 2048 blocks
        sample_max_v2<<<dim3(2048), 256, 0, stream>>>(featT, c8, vbf, 16, 256, 1024, 8, 4);
        gemm_mfma_silu<<<dim3(256 / 64, 1024 / 64, 2), 256, 0, stream>>>(
            w8bf, vbf, b8, bev8, 1024, 4096, 256);
    }
    // ================= validity mask (scale-2 coords only) =====================
    mask_kernel<<<dim3((2 * 16384 + 255) / 256), 256, 0, stream>>>(c2, mask, 16384);
}

// Round 4
// 291.909 us; speedup vs baseline: 2.7244x; 1.1918x over previous
//
#include <hip/hip_runtime.h>
#include <hip/hip_bf16.h>
#include <math.h>

namespace {

constexpr int B_ = 2;
constexpr int S_ = 4;
constexpr int Y_ = 4;

typedef short short8 __attribute__((ext_vector_type(8)));
typedef float floatx4 __attribute__((ext_vector_type(4)));

__device__ __forceinline__ unsigned short f2bf(float x) {
    union { float f; unsigned u; } a; a.f = x;
    unsigned r = a.u + 0x7fff + ((a.u >> 16) & 1);   // round-to-nearest-even
    return (unsigned short)(r >> 16);
}
__device__ __forceinline__ float bf2f(unsigned short h) {
    union { unsigned u; float f; } a; a.u = ((unsigned)h) << 16;
    return a.f;
}

// float -> bf16 bulk convert (n multiple of 1024, grid = n/1024 blocks of 256)
__global__ void cvt_bf16(const float* __restrict__ in, unsigned short* __restrict__ out) {
    long idx = ((long)blockIdx.x * 256 + threadIdx.x) * 4;
    float4 v = *reinterpret_cast<const float4*>(in + idx);
    ushort4 u;
    u.x = f2bf(v.x); u.y = f2bf(v.y); u.z = f2bf(v.z); u.w = f2bf(v.w);
    *reinterpret_cast<ushort4*>(out + idx) = u;
}

// feat (BS, C, P) f32 -> featT (BS, P, C) bf16.  32x32 LDS tiles. C,P % 32 == 0.
__global__ __launch_bounds__(256) void transpose_bf16(
    const float* __restrict__ in, unsigned short* __restrict__ out, int C, int P)
{
    __shared__ float tile[32][33];
    int bs = blockIdx.z;
    int pBase = blockIdx.x * 32;
    int cBase = blockIdx.y * 32;
    int tx = threadIdx.x & 31;
    int ty = threadIdx.x >> 5;   // 0..7
    const float* ip = in + ((size_t)bs * C + cBase) * P + pBase;
    #pragma unroll
    for (int r = 0; r < 32; r += 8)
        tile[ty + r][tx] = ip[(size_t)(ty + r) * P + tx];
    __syncthreads();
    unsigned short* op = out + ((size_t)bs * P + pBase) * C + cBase;
    #pragma unroll
    for (int r = 0; r < 32; r += 8)
        op[(size_t)(ty + r) * C + tx] = f2bf(tile[tx][ty + r]);
}

// One WAVE per (b, m, c-chunk of 64).  Corner positions/weights are wave-uniform;
// corner loads are coalesced over channels (featT is channels-last bf16).
__global__ __launch_bounds__(256) void sample_max_v2(
    const unsigned short* __restrict__ featT, // (BS, P, C) bf16
    const float* __restrict__ coords,         // (BS, Y*M, 2)
    unsigned short* __restrict__ vout,        // (B, M, K=4C) bf16
    int Wd, int M, int C, int logM, int logCc)
{
    int wid = (int)((blockIdx.x * 256 + threadIdx.x) >> 6);
    int lane = threadIdx.x & 63;
    int nc1 = (1 << logCc) - 1;
    int cchunk = wid & nc1;
    int m = (wid >> logCc) & (M - 1);
    int b = wid >> (logCc + logM);
    int c = cchunk * 64 + lane;
    int P = Wd * Wd;

    float best[4];
    #pragma unroll
    for (int y = 0; y < 4; ++y) {
        float bst = -3.4e38f;
        bool anyinv = false;
        #pragma unroll
        for (int s = 0; s < 4; ++s) {
            int bs = b * S_ + s;
            float2 g = ((const float2*)coords)[((size_t)bs << (logM + 2)) + ((size_t)y << logM) + m];
            bool valid = (g.x >= -1.f) && (g.x <= 1.f) && (g.y >= -1.f) && (g.y <= 1.f);
            if (!valid) { anyinv = true; continue; }
            float ix = (g.x + 1.f) * 0.5f * (float)(Wd - 1);
            float iy = (g.y + 1.f) * 0.5f * (float)(Wd - 1);
            float x0f = floorf(ix), y0f = floorf(iy);
            float wx = ix - x0f, wy = iy - y0f;
            int x0 = min(max((int)x0f, 0), Wd - 1);
            int x1 = min(x0 + 1, Wd - 1);
            int y0 = min(max((int)y0f, 0), Wd - 1);
            int y1 = min(y0 + 1, Wd - 1);
            const unsigned short* fp = featT + (size_t)bs * P * C + c;
            float v00 = bf2f(fp[(y0 * Wd + x0) * C]);
            float v01 = bf2f(fp[(y0 * Wd + x1) * C]);
            float v10 = bf2f(fp[(y1 * Wd + x0) * C]);
            float v11 = bf2f(fp[(y1 * Wd + x1) * C]);
            float samp = v00 * (1.f - wx) * (1.f - wy)
                       + v01 * wx        * (1.f - wy)
                       + v10 * (1.f - wx) * wy
                       + v11 * wx        * wy;
            bst = fmaxf(bst, samp);
        }
        if (anyinv) bst = fmaxf(bst, 0.f);
        best[y] = bst;
    }
    ushort4 o;
    o.x = f2bf(best[0]); o.y = f2bf(best[1]);
    o.z = f2bf(best[2]); o.w = f2bf(best[3]);
    *reinterpret_cast<ushort4*>(vout + (((size_t)b << logM) + m) * (C * 4) + c * 4) = o;
}

// ============================================================================
// Split-K, distance-2 pipelined MFMA GEMM.
// out[b,o,m] = silu(sum_k W[o,k]*V[b,m,k] + bias[o])   (kSplit==1, fused)
// partial[z= ks*B+b][o][m] = partial sums               (kSplit>1)
// 64x64 tile, BK=64, 256 threads = 4 waves (32x32 quadrant each).
// Double-buffered LDS (one barrier/iter) + 2 register prefetch sets.
// ============================================================================
#define GLOAD(s, it) do { \
    w##s##a = *reinterpret_cast<const float4*>(Wp + (size_t)row0 * K + (it) * 64 + kc); \
    w##s##b = *reinterpret_cast<const float4*>(Wp + (size_t)(row0 + 32) * K + (it) * 64 + kc); \
    v##s##a = *reinterpret_cast<const float4*>(Vp + (size_t)row0 * K + (it) * 64 + kc); \
    v##s##b = *reinterpret_cast<const float4*>(Vp + (size_t)(row0 + 32) * K + (it) * 64 + kc); \
} while (0)

#define LSTORE(s, buf) do { \
    *reinterpret_cast<float4*>(&As[buf][row0 * 72 + kc]) = w##s##a; \
    *reinterpret_cast<float4*>(&As[buf][(row0 + 32) * 72 + kc]) = w##s##b; \
    *reinterpret_cast<float4*>(&Bs[buf][row0 * 72 + kc]) = v##s##a; \
    *reinterpret_cast<float4*>(&Bs[buf][(row0 + 32) * 72 + kc]) = v##s##b; \
} while (0)

#define MFMA_STEP(buf) do { \
    _Pragma("unroll") \
    for (int kss = 0; kss < 64; kss += 32) { \
        short8 af0 = *reinterpret_cast<const short8*>(&As[buf][(wo + lr) * 72 + kss + quad * 8]); \
        short8 af1 = *reinterpret_cast<const short8*>(&As[buf][(wo + 16 + lr) * 72 + kss + quad * 8]); \
        short8 bf0 = *reinterpret_cast<const short8*>(&Bs[buf][(wm + lr) * 72 + kss + quad * 8]); \
        short8 bf1 = *reinterpret_cast<const short8*>(&Bs[buf][(wm + 16 + lr) * 72 + kss + quad * 8]); \
        acc[0][0] = __builtin_amdgcn_mfma_f32_16x16x32_bf16(af0, bf0, acc[0][0], 0, 0, 0); \
        acc[0][1] = __builtin_amdgcn_mfma_f32_16x16x32_bf16(af0, bf1, acc[0][1], 0, 0, 0); \
        acc[1][0] = __builtin_amdgcn_mfma_f32_16x16x32_bf16(af1, bf0, acc[1][0], 0, 0, 0); \
        acc[1][1] = __builtin_amdgcn_mfma_f32_16x16x32_bf16(af1, bf1, acc[1][1], 0, 0, 0); \
    } \
} while (0)

__global__ __launch_bounds__(256) void gemm_mfma_v2(
    const unsigned short* __restrict__ Wb,  // (N, K) bf16
    const unsigned short* __restrict__ Vb,  // (B, M, K) bf16
    const float* __restrict__ bias,         // (N)
    float* __restrict__ out,                // (B, N, M) if kSplit==1
    float* __restrict__ partial,            // (kSplit*B, N, M) if kSplit>1
    int N, int K, int M, int kSplit)
{
    __shared__ __align__(16) unsigned short As[2][64 * 72];
    __shared__ __align__(16) unsigned short Bs[2][64 * 72];

    const int z = blockIdx.z;
    const int b = z & 1;
    const int ks = z >> 1;
    const int Kspan = K / kSplit;        // multiple of 128 (nIter even)
    const int nIter = Kspan >> 6;

    const int mBase = blockIdx.x * 64;
    const int oBase = blockIdx.y * 64;
    const int tid = threadIdx.x;
    const int lane = tid & 63;
    const int wave = tid >> 6;
    const int wo = (wave >> 1) * 32;
    const int wm = (wave & 1) * 32;
    const int quad = lane >> 4;
    const int lr = lane & 15;
    const int row0 = tid >> 3;           // 0..31
    const int kc = (tid & 7) * 8;

    const unsigned short* Wp = Wb + (size_t)oBase * K + ks * Kspan;
    const unsigned short* Vp = Vb + ((size_t)b * M + mBase) * K + ks * Kspan;

    floatx4 acc[2][2] = {};
    float4 w0a, w0b, v0a, v0b;   // prefetch set 0
    float4 w1a, w1b, v1a, v1b;   // prefetch set 1

    GLOAD(0, 0);
    LSTORE(0, 0);
    GLOAD(1, 1);
    __syncthreads();

    for (int it = 0; it < nIter; it += 2) {
        // phase 0: compute buf0; set1 holds it+1
        MFMA_STEP(0);
        LSTORE(1, 1);
        if (it + 2 < nIter) GLOAD(0, it + 2);
        __syncthreads();
        // phase 1: compute buf1; set0 holds it+2 (if any)
        MFMA_STEP(1);
        if (it + 2 < nIter) {
            LSTORE(0, 0);
            if (it + 3 < nIter) GLOAD(1, it + 3);
            __syncthreads();
        }
    }

    if (kSplit == 1) {
        #pragma unroll
        for (int i = 0; i < 2; ++i)
            #pragma unroll
            for (int r = 0; r < 4; ++r) {
                int o = oBase + wo + i * 16 + quad * 4 + r;
                float bi = bias[o];
                #pragma unroll
                for (int j = 0; j < 2; ++j) {
                    int m = mBase + wm + j * 16 + lr;
                    float x = acc[i][j][r] + bi;
                    out[((size_t)b * N + o) * M + m] = x / (1.f + __expf(-x));
                }
            }
    } else {
        float* pp = partial + (size_t)z * N * M;
        #pragma unroll
        for (int i = 0; i < 2; ++i)
            #pragma unroll
            for (int r = 0; r < 4; ++r) {
                int o = oBase + wo + i * 16 + quad * 4 + r;
                #pragma unroll
                for (int j = 0; j < 2; ++j) {
                    int m = mBase + wm + j * 16 + lr;
                    pp[(size_t)o * M + m] = acc[i][j][r];
                }
            }
    }
}

// out[b,o,m] = silu(sum_ks partial[ks*B+b][o][m] + bias[o]); float4 per thread.
__global__ __launch_bounds__(256) void reduce_bias_silu(
    const float* __restrict__ partial, const float* __restrict__ bias,
    float* __restrict__ out, int N, int M, int kSplit)
{
    size_t idx = (size_t)blockIdx.x * 256 + threadIdx.x;   // over B*N*(M/4)
    int m4 = M >> 2;
    int mi = (int)(idx % m4);
    int o  = (int)((idx / m4) % N);
    int b  = (int)(idx / ((size_t)m4 * N));
    size_t base = ((size_t)b * N + o) * M + (size_t)mi * 4;
    size_t stride = (size_t)2 * N * M;
    float4 s = *reinterpret_cast<const float4*>(partial + base);
    for (int k = 1; k < kSplit; ++k) {
        float4 t = *reinterpret_cast<const float4*>(partial + base + (size_t)k * stride);
        s.x += t.x; s.y += t.y; s.z += t.z; s.w += t.w;
    }
    float bi = bias[o];
    float4 r;
    float xs[4] = {s.x + bi, s.y + bi, s.z + bi, s.w + bi};
    r.x = xs[0] / (1.f + __expf(-xs[0]));
    r.y = xs[1] / (1.f + __expf(-xs[1]));
    r.z = xs[2] / (1.f + __expf(-xs[2]));
    r.w = xs[3] / (1.f + __expf(-xs[3]));
    *reinterpret_cast<float4*>(out + base) = r;
}

// valid_vox_mask[b,n] = any_s valid(coords_s2[b*S+s, n])
__global__ void mask_kernel(const float* __restrict__ coords, // (B*S, Ntot, 2)
                            float* __restrict__ out,          // (B, Ntot)
                            int Ntot)
{
    int idx = blockIdx.x * blockDim.x + threadIdx.x;
    if (idx >= B_ * Ntot) return;
    int n = idx % Ntot;
    int b = idx / Ntot;
    float best = 0.f;
    #pragma unroll
    for (int s = 0; s < S_; ++s) {
        float2 g = ((const float2*)coords)[(long)(b * S_ + s) * Ntot + n];
        bool valid = (g.x >= -1.f) && (g.x <= 1.f) && (g.y >= -1.f) && (g.y <= 1.f);
        if (valid) best = 1.f;
    }
    out[idx] = best;
}

} // namespace

extern "C" void kernel_launch(void* const* d_in, const int* in_sizes, int n_in,
                              void* d_out, int out_size, void* d_ws, size_t ws_size,
                              hipStream_t stream)
{
    const float* x3 = (const float*)d_in[0];
    const float* x4 = (const float*)d_in[1];
    const float* x5 = (const float*)d_in[2];
    const float* c2 = (const float*)d_in[3];
    const float* c4 = (const float*)d_in[4];
    const float* c8 = (const float*)d_in[5];
    const float* w2 = (const float*)d_in[6];
    const float* b2 = (const float*)d_in[7];
    const float* w4 = (const float*)d_in[8];
    const float* b4 = (const float*)d_in[9];
    const float* w8 = (const float*)d_in[10];
    const float* b8 = (const float*)d_in[11];

    float* out  = (float*)d_out;
    float* bev2 = out;
    float* bev4 = bev2 + (long)2 * 256 * 64 * 64;
    float* bev8 = bev4 + (long)2 * 512 * 32 * 32;
    float* mask = bev8 + (long)2 * 1024 * 16 * 16;

    // ws layout (32 MB total, proven available):
    //   [0,16)  MB: V (sampled, bf16)
    //   [16,32) MB: featT (dead after sampler) / bf16 weights / split-K partials
    char* ws = (char*)d_ws;
    unsigned short* vbf = (unsigned short*)ws;
    char* F = ws + (16L << 20);

    // ================= scale 2: C=256, W=64, M=4096, K=1024, N=256, split=1 ====
    {
        unsigned short* featT = (unsigned short*)F;                 // [16,32) MB
        transpose_bf16<<<dim3(4096 / 32, 256 / 32, 8), 256, 0, stream>>>(x3, featT, 256, 4096);
        sample_max_v2<<<dim3(8192), 256, 0, stream>>>(featT, c2, vbf, 64, 4096, 256, 12, 2);
        unsigned short* w2bf = (unsigned short*)F;                  // featT dead; 0.5 MB
        cvt_bf16<<<dim3(256 * 1024 / 1024), 256, 0, stream>>>(w2, w2bf);
        gemm_mfma_v2<<<dim3(4096 / 64, 256 / 64, 2), 256, 0, stream>>>(
            w2bf, vbf, b2, bev2, nullptr, 256, 1024, 4096, 1);
    }
    // ================= scale 4: C=512, W=32, M=1024, K=2048, N=512, split=4 ====
    {
        unsigned short* featT = (unsigned short*)F;                 // [16,24) MB
        unsigned short* w4bf  = (unsigned short*)(ws + (24L << 20)); // [24,26) MB
        float* part4          = (float*)(ws + (8L << 20));           // [8,24) MB (featT dead)
        cvt_bf16<<<dim3(512 * 2048 / 1024), 256, 0, stream>>>(w4, w4bf);
        transpose_bf16<<<dim3(1024 / 32, 512 / 32, 8), 256, 0, stream>>>(x4, featT, 512, 1024);
        sample_max_v2<<<dim3(4096), 256, 0, stream>>>(featT, c4, vbf, 32, 1024, 512, 10, 3);
        gemm_mfma_v2<<<dim3(1024 / 64, 512 / 64, 2 * 4), 256, 0, stream>>>(
            w4bf, vbf, b4, nullptr, part4, 512, 2048, 1024, 4);
        reduce_bias_silu<<<dim3(2 * 512 * 1024 / 4 / 256), 256, 0, stream>>>(
            part4, b4, bev4, 512, 1024, 4);
    }
    // ================= scale 8: C=1024, W=16, M=256, K=4096, N=1024, split=8 ===
    {
        unsigned short* featT = (unsigned short*)F;                 // [16,20) MB
        unsigned short* w8bf  = (unsigned short*)(ws + (20L << 20)); // [20,28) MB
        float* part8          = (float*)(ws + (4L << 20));           // [4,20) MB (featT dead)
        cvt_bf16<<<dim3(1024 * 4096 / 1024), 256, 0, stream>>>(w8, w8bf);
        transpose_bf16<<<dim3(256 / 32, 1024 / 32, 8), 256, 0, stream>>>(x5, featT, 1024, 256);
        sample_max_v2<<<dim3(2048), 256, 0, stream>>>(featT, c8, vbf, 16, 256, 1024, 8, 4);
        gemm_mfma_v2<<<dim3(256 / 64, 1024 / 64, 2 * 8), 256, 0, stream>>>(
            w8bf, vbf, b8, nullptr, part8, 1024, 4096, 256, 8);
        reduce_bias_silu<<<dim3(2 * 1024 * 256 / 4 / 256), 256, 0, stream>>>(
            part8, b8, bev8, 1024, 256, 8);
    }
    // ================= validity mask (scale-2 coords only) =====================
    mask_kernel<<<dim3((2 * 16384 + 255) / 256), 256, 0, stream>>>(c2, mask, 16384);
}

// Round 5
// 250.485 us; speedup vs baseline: 3.1749x; 1.1654x over previous
//
#include <hip/hip_runtime.h>
#include <hip/hip_bf16.h>
#include <math.h>

namespace {

constexpr int B_ = 2;
constexpr int S_ = 4;
constexpr int Y_ = 4;

typedef short short8 __attribute__((ext_vector_type(8)));
typedef float floatx4 __attribute__((ext_vector_type(4)));
typedef unsigned short ushort4v __attribute__((ext_vector_type(4)));
typedef unsigned short ushort8v __attribute__((ext_vector_type(8)));

__device__ __forceinline__ unsigned short f2bf(float x) {
    union { float f; unsigned u; } a; a.f = x;
    unsigned r = a.u + 0x7fff + ((a.u >> 16) & 1);   // round-to-nearest-even
    return (unsigned short)(r >> 16);
}
__device__ __forceinline__ float bf2f(unsigned short h) {
    union { unsigned u; float f; } a; a.u = ((unsigned)h) << 16;
    return a.f;
}

// float -> bf16 bulk convert (n multiple of 1024, grid = n/1024 blocks of 256)
__global__ void cvt_bf16(const float* __restrict__ in, unsigned short* __restrict__ out) {
    long idx = ((long)blockIdx.x * 256 + threadIdx.x) * 4;
    float4 v = *reinterpret_cast<const float4*>(in + idx);
    ushort4 u;
    u.x = f2bf(v.x); u.y = f2bf(v.y); u.z = f2bf(v.z); u.w = f2bf(v.w);
    *reinterpret_cast<ushort4*>(out + idx) = u;
}

// feat (BS, C, P) f32 -> featT (BS, P, C) bf16.  32x32 LDS tiles. C,P % 32 == 0.
__global__ __launch_bounds__(256) void transpose_bf16(
    const float* __restrict__ in, unsigned short* __restrict__ out, int C, int P)
{
    __shared__ float tile[32][33];
    int bs = blockIdx.z;
    int pBase = blockIdx.x * 32;
    int cBase = blockIdx.y * 32;
    int tx = threadIdx.x & 31;
    int ty = threadIdx.x >> 5;   // 0..7
    const float* ip = in + ((size_t)bs * C + cBase) * P + pBase;
    #pragma unroll
    for (int r = 0; r < 32; r += 8)
        tile[ty + r][tx] = ip[(size_t)(ty + r) * P + tx];
    __syncthreads();
    unsigned short* op = out + ((size_t)bs * P + pBase) * C + cBase;
    #pragma unroll
    for (int r = 0; r < 32; r += 8)
        op[(size_t)(ty + r) * C + tx] = f2bf(tile[tx][ty + r]);
}

// One WAVE per (b, m, 256-channel chunk).  Lane handles 4 consecutive channels
// (ushort4 corner loads, 8 B/lane -> 512 B/wave/corner).  Address/valid math is
// wave-uniform and computed once per (b,m); per-channel cost = 4 FMA + max.
// Output k = (c+j)*4 + y -> each lane writes 16 consecutive bf16 (32 B).
__global__ __launch_bounds__(256) void sample_max_v3(
    const unsigned short* __restrict__ featT, // (BS, P, C) bf16
    const float* __restrict__ coords,         // (BS, Y*M, 2)
    unsigned short* __restrict__ vout,        // (B, M, K=4C) bf16
    int Wd, int M, int C, int logM, int logCc) // logCc = log2(C/256)
{
    int wid = (int)((blockIdx.x * 256 + threadIdx.x) >> 6);
    int lane = threadIdx.x & 63;
    int chunk = wid & ((1 << logCc) - 1);
    int m = (wid >> logCc) & (M - 1);
    int b = wid >> (logCc + logM);
    int c = chunk * 256 + lane * 4;
    int P = Wd * Wd;

    unsigned short outv[16];
    #pragma unroll
    for (int y = 0; y < 4; ++y) {
        float bst0 = -3.4e38f, bst1 = -3.4e38f, bst2 = -3.4e38f, bst3 = -3.4e38f;
        bool anyinv = false;
        #pragma unroll
        for (int s = 0; s < 4; ++s) {
            int bs = b * S_ + s;
            float2 g = ((const float2*)coords)[((size_t)bs << (logM + 2)) + ((size_t)y << logM) + m];
            bool valid = (g.x >= -1.f) && (g.x <= 1.f) && (g.y >= -1.f) && (g.y <= 1.f);
            if (!valid) { anyinv = true; continue; }
            float ix = (g.x + 1.f) * 0.5f * (float)(Wd - 1);
            float iy = (g.y + 1.f) * 0.5f * (float)(Wd - 1);
            float x0f = floorf(ix), y0f = floorf(iy);
            float wx = ix - x0f, wy = iy - y0f;
            int x0 = min(max((int)x0f, 0), Wd - 1);
            int x1 = min(x0 + 1, Wd - 1);
            int y0 = min(max((int)y0f, 0), Wd - 1);
            int y1 = min(y0 + 1, Wd - 1);
            float w00 = (1.f - wx) * (1.f - wy);
            float w01 = wx * (1.f - wy);
            float w10 = (1.f - wx) * wy;
            float w11 = wx * wy;
            const unsigned short* fp = featT + (size_t)bs * P * C + c;
            ushort4v u00 = *reinterpret_cast<const ushort4v*>(fp + (size_t)(y0 * Wd + x0) * C);
            ushort4v u01 = *reinterpret_cast<const ushort4v*>(fp + (size_t)(y0 * Wd + x1) * C);
            ushort4v u10 = *reinterpret_cast<const ushort4v*>(fp + (size_t)(y1 * Wd + x0) * C);
            ushort4v u11 = *reinterpret_cast<const ushort4v*>(fp + (size_t)(y1 * Wd + x1) * C);
            bst0 = fmaxf(bst0, bf2f(u00[0]) * w00 + bf2f(u01[0]) * w01 + bf2f(u10[0]) * w10 + bf2f(u11[0]) * w11);
            bst1 = fmaxf(bst1, bf2f(u00[1]) * w00 + bf2f(u01[1]) * w01 + bf2f(u10[1]) * w10 + bf2f(u11[1]) * w11);
            bst2 = fmaxf(bst2, bf2f(u00[2]) * w00 + bf2f(u01[2]) * w01 + bf2f(u10[2]) * w10 + bf2f(u11[2]) * w11);
            bst3 = fmaxf(bst3, bf2f(u00[3]) * w00 + bf2f(u01[3]) * w01 + bf2f(u10[3]) * w10 + bf2f(u11[3]) * w11);
        }
        if (anyinv) {
            bst0 = fmaxf(bst0, 0.f); bst1 = fmaxf(bst1, 0.f);
            bst2 = fmaxf(bst2, 0.f); bst3 = fmaxf(bst3, 0.f);
        }
        outv[0 * 4 + y] = f2bf(bst0);
        outv[1 * 4 + y] = f2bf(bst1);
        outv[2 * 4 + y] = f2bf(bst2);
        outv[3 * 4 + y] = f2bf(bst3);
    }
    size_t base = (((size_t)b << logM) + m) * ((size_t)C * 4) + chunk * 1024 + lane * 16;
    ushort8v o0, o1;
    #pragma unroll
    for (int t = 0; t < 8; ++t) { o0[t] = outv[t]; o1[t] = outv[8 + t]; }
    *reinterpret_cast<ushort8v*>(vout + base)     = o0;
    *reinterpret_cast<ushort8v*>(vout + base + 8) = o1;
}

// ============================================================================
// Split-K, distance-2 pipelined MFMA GEMM (unchanged from round 4).
// ============================================================================
#define GLOAD(s, it) do { \
    w##s##a = *reinterpret_cast<const float4*>(Wp + (size_t)row0 * K + (it) * 64 + kc); \
    w##s##b = *reinterpret_cast<const float4*>(Wp + (size_t)(row0 + 32) * K + (it) * 64 + kc); \
    v##s##a = *reinterpret_cast<const float4*>(Vp + (size_t)row0 * K + (it) * 64 + kc); \
    v##s##b = *reinterpret_cast<const float4*>(Vp + (size_t)(row0 + 32) * K + (it) * 64 + kc); \
} while (0)

#define LSTORE(s, buf) do { \
    *reinterpret_cast<float4*>(&As[buf][row0 * 72 + kc]) = w##s##a; \
    *reinterpret_cast<float4*>(&As[buf][(row0 + 32) * 72 + kc]) = w##s##b; \
    *reinterpret_cast<float4*>(&Bs[buf][row0 * 72 + kc]) = v##s##a; \
    *reinterpret_cast<float4*>(&Bs[buf][(row0 + 32) * 72 + kc]) = v##s##b; \
} while (0)

#define MFMA_STEP(buf) do { \
    _Pragma("unroll") \
    for (int kss = 0; kss < 64; kss += 32) { \
        short8 af0 = *reinterpret_cast<const short8*>(&As[buf][(wo + lr) * 72 + kss + quad * 8]); \
        short8 af1 = *reinterpret_cast<const short8*>(&As[buf][(wo + 16 + lr) * 72 + kss + quad * 8]); \
        short8 bf0 = *reinterpret_cast<const short8*>(&Bs[buf][(wm + lr) * 72 + kss + quad * 8]); \
        short8 bf1 = *reinterpret_cast<const short8*>(&Bs[buf][(wm + 16 + lr) * 72 + kss + quad * 8]); \
        acc[0][0] = __builtin_amdgcn_mfma_f32_16x16x32_bf16(af0, bf0, acc[0][0], 0, 0, 0); \
        acc[0][1] = __builtin_amdgcn_mfma_f32_16x16x32_bf16(af0, bf1, acc[0][1], 0, 0, 0); \
        acc[1][0] = __builtin_amdgcn_mfma_f32_16x16x32_bf16(af1, bf0, acc[1][0], 0, 0, 0); \
        acc[1][1] = __builtin_amdgcn_mfma_f32_16x16x32_bf16(af1, bf1, acc[1][1], 0, 0, 0); \
    } \
} while (0)

__global__ __launch_bounds__(256) void gemm_mfma_v2(
    const unsigned short* __restrict__ Wb,  // (N, K) bf16
    const unsigned short* __restrict__ Vb,  // (B, M, K) bf16
    const float* __restrict__ bias,         // (N)
    float* __restrict__ out,                // (B, N, M) if kSplit==1
    float* __restrict__ partial,            // (kSplit*B, N, M) if kSplit>1
    int N, int K, int M, int kSplit)
{
    __shared__ __align__(16) unsigned short As[2][64 * 72];
    __shared__ __align__(16) unsigned short Bs[2][64 * 72];

    const int z = blockIdx.z;
    const int b = z & 1;
    const int ks = z >> 1;
    const int Kspan = K / kSplit;        // multiple of 128 (nIter even)
    const int nIter = Kspan >> 6;

    const int mBase = blockIdx.x * 64;
    const int oBase = blockIdx.y * 64;
    const int tid = threadIdx.x;
    const int lane = tid & 63;
    const int wave = tid >> 6;
    const int wo = (wave >> 1) * 32;
    const int wm = (wave & 1) * 32;
    const int quad = lane >> 4;
    const int lr = lane & 15;
    const int row0 = tid >> 3;           // 0..31
    const int kc = (tid & 7) * 8;

    const unsigned short* Wp = Wb + (size_t)oBase * K + ks * Kspan;
    const unsigned short* Vp = Vb + ((size_t)b * M + mBase) * K + ks * Kspan;

    floatx4 acc[2][2] = {};
    float4 w0a, w0b, v0a, v0b;   // prefetch set 0
    float4 w1a, w1b, v1a, v1b;   // prefetch set 1

    GLOAD(0, 0);
    LSTORE(0, 0);
    GLOAD(1, 1);
    __syncthreads();

    for (int it = 0; it < nIter; it += 2) {
        MFMA_STEP(0);
        LSTORE(1, 1);
        if (it + 2 < nIter) GLOAD(0, it + 2);
        __syncthreads();
        MFMA_STEP(1);
        if (it + 2 < nIter) {
            LSTORE(0, 0);
            if (it + 3 < nIter) GLOAD(1, it + 3);
            __syncthreads();
        }
    }

    if (kSplit == 1) {
        #pragma unroll
        for (int i = 0; i < 2; ++i)
            #pragma unroll
            for (int r = 0; r < 4; ++r) {
                int o = oBase + wo + i * 16 + quad * 4 + r;
                float bi = bias[o];
                #pragma unroll
                for (int j = 0; j < 2; ++j) {
                    int m = mBase + wm + j * 16 + lr;
                    float x = acc[i][j][r] + bi;
                    out[((size_t)b * N + o) * M + m] = x / (1.f + __expf(-x));
                }
            }
    } else {
        float* pp = partial + (size_t)z * N * M;
        #pragma unroll
        for (int i = 0; i < 2; ++i)
            #pragma unroll
            for (int r = 0; r < 4; ++r) {
                int o = oBase + wo + i * 16 + quad * 4 + r;
                #pragma unroll
                for (int j = 0; j < 2; ++j) {
                    int m = mBase + wm + j * 16 + lr;
                    pp[(size_t)o * M + m] = acc[i][j][r];
                }
            }
    }
}

// out[b,o,m] = silu(sum_ks partial[ks*B+b][o][m] + bias[o]); float4 per thread.
__global__ __launch_bounds__(256) void reduce_bias_silu(
    const float* __restrict__ partial, const float* __restrict__ bias,
    float* __restrict__ out, int N, int M, int kSplit)
{
    size_t idx = (size_t)blockIdx.x * 256 + threadIdx.x;   // over B*N*(M/4)
    int m4 = M >> 2;
    int mi = (int)(idx % m4);
    int o  = (int)((idx / m4) % N);
    int b  = (int)(idx / ((size_t)m4 * N));
    size_t base = ((size_t)b * N + o) * M + (size_t)mi * 4;
    size_t stride = (size_t)2 * N * M;
    float4 s = *reinterpret_cast<const float4*>(partial + base);
    for (int k = 1; k < kSplit; ++k) {
        float4 t = *reinterpret_cast<const float4*>(partial + base + (size_t)k * stride);
        s.x += t.x; s.y += t.y; s.z += t.z; s.w += t.w;
    }
    float bi = bias[o];
    float4 r;
    float xs[4] = {s.x + bi, s.y + bi, s.z + bi, s.w + bi};
    r.x = xs[0] / (1.f + __expf(-xs[0]));
    r.y = xs[1] / (1.f + __expf(-xs[1]));
    r.z = xs[2] / (1.f + __expf(-xs[2]));
    r.w = xs[3] / (1.f + __expf(-xs[3]));
    *reinterpret_cast<float4*>(out + base) = r;
}

// valid_vox_mask[b,n] = any_s valid(coords_s2[b*S+s, n])
__global__ void mask_kernel(const float* __restrict__ coords, // (B*S, Ntot, 2)
                            float* __restrict__ out,          // (B, Ntot)
                            int Ntot)
{
    int idx = blockIdx.x * blockDim.x + threadIdx.x;
    if (idx >= B_ * Ntot) return;
    int n = idx % Ntot;
    int b = idx / Ntot;
    float best = 0.f;
    #pragma unroll
    for (int s = 0; s < S_; ++s) {
        float2 g = ((const float2*)coords)[(long)(b * S_ + s) * Ntot + n];
        bool valid = (g.x >= -1.f) && (g.x <= 1.f) && (g.y >= -1.f) && (g.y <= 1.f);
        if (valid) best = 1.f;
    }
    out[idx] = best;
}

} // namespace

extern "C" void kernel_launch(void* const* d_in, const int* in_sizes, int n_in,
                              void* d_out, int out_size, void* d_ws, size_t ws_size,
                              hipStream_t stream)
{
    const float* x3 = (const float*)d_in[0];
    const float* x4 = (const float*)d_in[1];
    const float* x5 = (const float*)d_in[2];
    const float* c2 = (const float*)d_in[3];
    const float* c4 = (const float*)d_in[4];
    const float* c8 = (const float*)d_in[5];
    const float* w2 = (const float*)d_in[6];
    const float* b2 = (const float*)d_in[7];
    const float* w4 = (const float*)d_in[8];
    const float* b4 = (const float*)d_in[9];
    const float* w8 = (const float*)d_in[10];
    const float* b8 = (const float*)d_in[11];

    float* out  = (float*)d_out;
    float* bev2 = out;
    float* bev4 = bev2 + (long)2 * 256 * 64 * 64;
    float* bev8 = bev4 + (long)2 * 512 * 32 * 32;
    float* mask = bev8 + (long)2 * 1024 * 16 * 16;

    // ws layout (32 MB total, proven available):
    //   [0,16)  MB: V (sampled, bf16)
    //   [16,32) MB: featT (dead after sampler) / bf16 weights / split-K partials
    char* ws = (char*)d_ws;
    unsigned short* vbf = (unsigned short*)ws;
    char* F = ws + (16L << 20);

    // ================= scale 2: C=256, W=64, M=4096, K=1024, N=256, split=1 ====
    {
        unsigned short* featT = (unsigned short*)F;                 // [16,32) MB
        transpose_bf16<<<dim3(4096 / 32, 256 / 32, 8), 256, 0, stream>>>(x3, featT, 256, 4096);
        // waves = B*M*(C/256) = 2*4096*1 = 8192 -> 2048 blocks
        sample_max_v3<<<dim3(2048), 256, 0, stream>>>(featT, c2, vbf, 64, 4096, 256, 12, 0);
        unsigned short* w2bf = (unsigned short*)F;                  // featT dead; 0.5 MB
        cvt_bf16<<<dim3(256 * 1024 / 1024), 256, 0, stream>>>(w2, w2bf);
        gemm_mfma_v2<<<dim3(4096 / 64, 256 / 64, 2), 256, 0, stream>>>(
            w2bf, vbf, b2, bev2, nullptr, 256, 1024, 4096, 1);
    }
    // ================= scale 4: C=512, W=32, M=1024, K=2048, N=512, split=4 ====
    {
        unsigned short* featT = (unsigned short*)F;                 // [16,24) MB
        unsigned short* w4bf  = (unsigned short*)(ws + (24L << 20)); // [24,26) MB
        float* part4          = (float*)(ws + (8L << 20));           // [8,24) MB (featT dead)
        cvt_bf16<<<dim3(512 * 2048 / 1024), 256, 0, stream>>>(w4, w4bf);
        transpose_bf16<<<dim3(1024 / 32, 512 / 32, 8), 256, 0, stream>>>(x4, featT, 512, 1024);
        // waves = 2*1024*2 = 4096 -> 1024 blocks
        sample_max_v3<<<dim3(1024), 256, 0, stream>>>(featT, c4, vbf, 32, 1024, 512, 10, 1);
        gemm_mfma_v2<<<dim3(1024 / 64, 512 / 64, 2 * 4), 256, 0, stream>>>(
            w4bf, vbf, b4, nullptr, part4, 512, 2048, 1024, 4);
        reduce_bias_silu<<<dim3(2 * 512 * 1024 / 4 / 256), 256, 0, stream>>>(
            part4, b4, bev4, 512, 1024, 4);
    }
    // ================= scale 8: C=1024, W=16, M=256, K=4096, N=1024, split=8 ===
    {
        unsigned short* featT = (unsigned short*)F;                 // [16,20) MB
        unsigned short* w8bf  = (unsigned short*)(ws + (20L << 20)); // [20,28) MB
        float* part8          = (float*)(ws + (4L << 20));           // [4,20) MB (featT dead)
        cvt_bf16<<<dim3(1024 * 4096 / 1024), 256, 0, stream>>>(w8, w8bf);
        transpose_bf16<<<dim3(256 / 32, 1024 / 32, 8), 256, 0, stream>>>(x5, featT, 1024, 256);
        // waves = 2*256*4 = 2048 -> 512 blocks
        sample_max_v3<<<dim3(512), 256, 0, stream>>>(featT, c8, vbf, 16, 256, 1024, 8, 2);
        gemm_mfma_v2<<<dim3(256 / 64, 1024 / 64, 2 * 8), 256, 0, stream>>>(
            w8bf, vbf, b8, nullptr, part8, 1024, 4096, 256, 8);
        reduce_bias_silu<<<dim3(2 * 1024 * 256 / 4 / 256), 256, 0, stream>>>(
            part8, b8, bev8, 1024, 256, 8);
    }
    // ================= validity mask (scale-2 coords only) =====================
    mask_kernel<<<dim3((2 * 16384 + 255) / 256), 256, 0, stream>>>(c2, mask, 16384);
}

// Round 6
// 209.995 us; speedup vs baseline: 3.7871x; 1.1928x over previous
//
#include <hip/hip_runtime.h>
#include <hip/hip_bf16.h>
#include <math.h>

namespace {

constexpr int B_ = 2;
constexpr int S_ = 4;

typedef short short8 __attribute__((ext_vector_type(8)));
typedef float floatx4 __attribute__((ext_vector_type(4)));
typedef unsigned short ushort4v __attribute__((ext_vector_type(4)));
typedef unsigned short ushort8v __attribute__((ext_vector_type(8)));

__device__ __forceinline__ unsigned short f2bf(float x) {
    union { float f; unsigned u; } a; a.f = x;
    unsigned r = a.u + 0x7fff + ((a.u >> 16) & 1);   // round-to-nearest-even
    return (unsigned short)(r >> 16);
}
__device__ __forceinline__ float bf2f(unsigned short h) {
    union { unsigned u; float f; } a; a.u = ((unsigned)h) << 16;
    return a.f;
}

// ============================ PHASE 1: transpose ============================
// feat (BS, C, P) f32 -> featT (BS, P, C) bf16, 32x32 LDS tiles.
// All three scales in one launch; per-block scale decoded from blockIdx.
__device__ __forceinline__ void transp_tile(
    const float* __restrict__ in, unsigned short* __restrict__ out,
    int C, int P, int bs, int pBase, int cBase, int tid, float (*tile)[33])
{
    int tx = tid & 31;
    int ty = tid >> 5;   // 0..7
    const float* ip = in + ((size_t)bs * C + cBase) * P + pBase;
    #pragma unroll
    for (int r = 0; r < 32; r += 8)
        tile[ty + r][tx] = ip[(size_t)(ty + r) * P + tx];
    __syncthreads();
    unsigned short* op = out + ((size_t)bs * P + pBase) * C + cBase;
    #pragma unroll
    for (int r = 0; r < 32; r += 8)
        op[(size_t)(ty + r) * C + tx] = f2bf(tile[tx][ty + r]);
}

// blocks: s2 [0,8192)  s4 [8192,12288)  s8 [12288,14336)
__global__ __launch_bounds__(256) void transpose_all(
    const float* __restrict__ x3, const float* __restrict__ x4, const float* __restrict__ x5,
    unsigned short* __restrict__ f2, unsigned short* __restrict__ f4, unsigned short* __restrict__ f8)
{
    __shared__ float tile[32][33];
    int bid = blockIdx.x;
    int tid = threadIdx.x;
    if (bid < 8192) {                    // s2: C=256 P=4096, tilesP=128, per-bs=1024
        int local = bid;
        int bs = local >> 10, r = local & 1023;
        transp_tile(x3, f2, 256, 4096, bs, (r & 127) * 32, (r >> 7) * 32, tid, tile);
    } else if (bid < 12288) {            // s4: C=512 P=1024, tilesP=32, per-bs=512
        int local = bid - 8192;
        int bs = local >> 9, r = local & 511;
        transp_tile(x4, f4, 512, 1024, bs, (r & 31) * 32, (r >> 5) * 32, tid, tile);
    } else {                             // s8: C=1024 P=256, tilesP=8, per-bs=256
        int local = bid - 12288;
        int bs = local >> 8, r = local & 255;
        transp_tile(x5, f8, 1024, 256, bs, (r & 7) * 32, (r >> 3) * 32, tid, tile);
    }
}

// ============================ PHASE 2: weight cvt ===========================
// blocks: w2 [0,256) w4 [256,1280) w8 [1280,5376); 1024 elems/block.
__global__ __launch_bounds__(256) void cvt_w_all(
    const float* __restrict__ w2, const float* __restrict__ w4, const float* __restrict__ w8,
    unsigned short* __restrict__ o2, unsigned short* __restrict__ o4, unsigned short* __restrict__ o8)
{
    int bid = blockIdx.x;
    const float* in; unsigned short* out; int local;
    if (bid < 256)       { in = w2; out = o2; local = bid; }
    else if (bid < 1280) { in = w4; out = o4; local = bid - 256; }
    else                 { in = w8; out = o8; local = bid - 1280; }
    long idx = ((long)local * 256 + threadIdx.x) * 4;
    float4 v = *reinterpret_cast<const float4*>(in + idx);
    ushort4 u;
    u.x = f2bf(v.x); u.y = f2bf(v.y); u.z = f2bf(v.z); u.w = f2bf(v.w);
    *reinterpret_cast<ushort4*>(out + idx) = u;
}

// ============================ PHASE 3: sample+max ===========================
// One WAVE per (b, m, 256-channel chunk), 4 channels/lane, ushort4 corner loads.
__device__ __forceinline__ void sample_wave(
    const unsigned short* __restrict__ featT, const float* __restrict__ coords,
    unsigned short* __restrict__ vout,
    int Wd, int M, int C, int logM, int logCc, int wid, int lane)
{
    int chunk = wid & ((1 << logCc) - 1);
    int m = (wid >> logCc) & (M - 1);
    int b = wid >> (logCc + logM);
    int c = chunk * 256 + lane * 4;
    int P = Wd * Wd;

    unsigned short outv[16];
    #pragma unroll
    for (int y = 0; y < 4; ++y) {
        float bst0 = -3.4e38f, bst1 = -3.4e38f, bst2 = -3.4e38f, bst3 = -3.4e38f;
        bool anyinv = false;
        #pragma unroll
        for (int s = 0; s < 4; ++s) {
            int bs = b * S_ + s;
            float2 g = ((const float2*)coords)[((size_t)bs << (logM + 2)) + ((size_t)y << logM) + m];
            bool valid = (g.x >= -1.f) && (g.x <= 1.f) && (g.y >= -1.f) && (g.y <= 1.f);
            if (!valid) { anyinv = true; continue; }
            float ix = (g.x + 1.f) * 0.5f * (float)(Wd - 1);
            float iy = (g.y + 1.f) * 0.5f * (float)(Wd - 1);
            float x0f = floorf(ix), y0f = floorf(iy);
            float wx = ix - x0f, wy = iy - y0f;
            int x0 = min(max((int)x0f, 0), Wd - 1);
            int x1 = min(x0 + 1, Wd - 1);
            int y0 = min(max((int)y0f, 0), Wd - 1);
            int y1 = min(y0 + 1, Wd - 1);
            float w00 = (1.f - wx) * (1.f - wy);
            float w01 = wx * (1.f - wy);
            float w10 = (1.f - wx) * wy;
            float w11 = wx * wy;
            const unsigned short* fp = featT + (size_t)bs * P * C + c;
            ushort4v u00 = *reinterpret_cast<const ushort4v*>(fp + (size_t)(y0 * Wd + x0) * C);
            ushort4v u01 = *reinterpret_cast<const ushort4v*>(fp + (size_t)(y0 * Wd + x1) * C);
            ushort4v u10 = *reinterpret_cast<const ushort4v*>(fp + (size_t)(y1 * Wd + x0) * C);
            ushort4v u11 = *reinterpret_cast<const ushort4v*>(fp + (size_t)(y1 * Wd + x1) * C);
            bst0 = fmaxf(bst0, bf2f(u00[0]) * w00 + bf2f(u01[0]) * w01 + bf2f(u10[0]) * w10 + bf2f(u11[0]) * w11);
            bst1 = fmaxf(bst1, bf2f(u00[1]) * w00 + bf2f(u01[1]) * w01 + bf2f(u10[1]) * w10 + bf2f(u11[1]) * w11);
            bst2 = fmaxf(bst2, bf2f(u00[2]) * w00 + bf2f(u01[2]) * w01 + bf2f(u10[2]) * w10 + bf2f(u11[2]) * w11);
            bst3 = fmaxf(bst3, bf2f(u00[3]) * w00 + bf2f(u01[3]) * w01 + bf2f(u10[3]) * w10 + bf2f(u11[3]) * w11);
        }
        if (anyinv) {
            bst0 = fmaxf(bst0, 0.f); bst1 = fmaxf(bst1, 0.f);
            bst2 = fmaxf(bst2, 0.f); bst3 = fmaxf(bst3, 0.f);
        }
        outv[0 * 4 + y] = f2bf(bst0);
        outv[1 * 4 + y] = f2bf(bst1);
        outv[2 * 4 + y] = f2bf(bst2);
        outv[3 * 4 + y] = f2bf(bst3);
    }
    size_t base = (((size_t)b << logM) + m) * ((size_t)C * 4) + chunk * 1024 + lane * 16;
    ushort8v o0, o1;
    #pragma unroll
    for (int t = 0; t < 8; ++t) { o0[t] = outv[t]; o1[t] = outv[8 + t]; }
    *reinterpret_cast<ushort8v*>(vout + base)     = o0;
    *reinterpret_cast<ushort8v*>(vout + base + 8) = o1;
}

// waves: s2 [0,8192) s4 [8192,12288) s8 [12288,14336) -> 3584 blocks
__global__ __launch_bounds__(256) void sample_all(
    const unsigned short* __restrict__ f2, const unsigned short* __restrict__ f4,
    const unsigned short* __restrict__ f8,
    const float* __restrict__ c2, const float* __restrict__ c4, const float* __restrict__ c8,
    unsigned short* __restrict__ v2, unsigned short* __restrict__ v4,
    unsigned short* __restrict__ v8)
{
    int gw = (int)((blockIdx.x * 256 + threadIdx.x) >> 6);
    int lane = threadIdx.x & 63;
    if (gw < 8192)
        sample_wave(f2, c2, v2, 64, 4096, 256, 12, 0, gw, lane);
    else if (gw < 12288)
        sample_wave(f4, c4, v4, 32, 1024, 512, 10, 1, gw - 8192, lane);
    else
        sample_wave(f8, c8, v8, 16, 256, 1024, 8, 2, gw - 12288, lane);
}

// ============================ PHASE 4: GEMM =================================
#define GLOAD(s, it) do { \
    w##s##a = *reinterpret_cast<const float4*>(Wp + (size_t)row0 * K + (it) * 64 + kc); \
    w##s##b = *reinterpret_cast<const float4*>(Wp + (size_t)(row0 + 32) * K + (it) * 64 + kc); \
    v##s##a = *reinterpret_cast<const float4*>(Vp + (size_t)row0 * K + (it) * 64 + kc); \
    v##s##b = *reinterpret_cast<const float4*>(Vp + (size_t)(row0 + 32) * K + (it) * 64 + kc); \
} while (0)

#define LSTORE(s, buf) do { \
    *reinterpret_cast<float4*>(&As[buf][row0 * 72 + kc]) = w##s##a; \
    *reinterpret_cast<float4*>(&As[buf][(row0 + 32) * 72 + kc]) = w##s##b; \
    *reinterpret_cast<float4*>(&Bs[buf][row0 * 72 + kc]) = v##s##a; \
    *reinterpret_cast<float4*>(&Bs[buf][(row0 + 32) * 72 + kc]) = v##s##b; \
} while (0)

#define MFMA_STEP(buf) do { \
    _Pragma("unroll") \
    for (int kss = 0; kss < 64; kss += 32) { \
        short8 af0 = *reinterpret_cast<const short8*>(&As[buf][(wo + lr) * 72 + kss + quad * 8]); \
        short8 af1 = *reinterpret_cast<const short8*>(&As[buf][(wo + 16 + lr) * 72 + kss + quad * 8]); \
        short8 bf0 = *reinterpret_cast<const short8*>(&Bs[buf][(wm + lr) * 72 + kss + quad * 8]); \
        short8 bf1 = *reinterpret_cast<const short8*>(&Bs[buf][(wm + 16 + lr) * 72 + kss + quad * 8]); \
        acc[0][0] = __builtin_amdgcn_mfma_f32_16x16x32_bf16(af0, bf0, acc[0][0], 0, 0, 0); \
        acc[0][1] = __builtin_amdgcn_mfma_f32_16x16x32_bf16(af0, bf1, acc[0][1], 0, 0, 0); \
        acc[1][0] = __builtin_amdgcn_mfma_f32_16x16x32_bf16(af1, bf0, acc[1][0], 0, 0, 0); \
        acc[1][1] = __builtin_amdgcn_mfma_f32_16x16x32_bf16(af1, bf1, acc[1][1], 0, 0, 0); \
    } \
} while (0)

// 64x64 tile, BK=64, double-buffered LDS + 2 register prefetch sets.
__device__ __forceinline__ void gemm_tile(
    const unsigned short* __restrict__ Wb, const unsigned short* __restrict__ Vb,
    const float* __restrict__ bias, float* __restrict__ out, float* __restrict__ partial,
    int N, int K, int M, int kSplit, int local, int logMt, int logNt,
    int tid, unsigned short (*As)[64 * 72], unsigned short (*Bs)[64 * 72])
{
    const int mTile = local & ((1 << logMt) - 1);
    const int rest  = local >> logMt;
    const int oTile = rest & ((1 << logNt) - 1);
    const int z     = rest >> logNt;
    const int b = z & 1;
    const int ks = z >> 1;
    const int Kspan = K / kSplit;
    const int nIter = Kspan >> 6;       // even for all scales

    const int mBase = mTile * 64;
    const int oBase = oTile * 64;
    const int lane = tid & 63;
    const int wave = tid >> 6;
    const int wo = (wave >> 1) * 32;
    const int wm = (wave & 1) * 32;
    const int quad = lane >> 4;
    const int lr = lane & 15;
    const int row0 = tid >> 3;           // 0..31
    const int kc = (tid & 7) * 8;

    const unsigned short* Wp = Wb + (size_t)oBase * K + ks * Kspan;
    const unsigned short* Vp = Vb + ((size_t)b * M + mBase) * K + ks * Kspan;

    floatx4 acc[2][2] = {};
    float4 w0a, w0b, v0a, v0b;
    float4 w1a, w1b, v1a, v1b;

    GLOAD(0, 0);
    LSTORE(0, 0);
    GLOAD(1, 1);
    __syncthreads();

    for (int it = 0; it < nIter; it += 2) {
        MFMA_STEP(0);
        LSTORE(1, 1);
        if (it + 2 < nIter) GLOAD(0, it + 2);
        __syncthreads();
        MFMA_STEP(1);
        if (it + 2 < nIter) {
            LSTORE(0, 0);
            if (it + 3 < nIter) GLOAD(1, it + 3);
            __syncthreads();
        }
    }

    if (kSplit == 1) {
        #pragma unroll
        for (int i = 0; i < 2; ++i)
            #pragma unroll
            for (int r = 0; r < 4; ++r) {
                int o = oBase + wo + i * 16 + quad * 4 + r;
                float bi = bias[o];
                #pragma unroll
                for (int j = 0; j < 2; ++j) {
                    int m = mBase + wm + j * 16 + lr;
                    float x = acc[i][j][r] + bi;
                    out[((size_t)b * N + o) * M + m] = x / (1.f + __expf(-x));
                }
            }
    } else {
        float* pp = partial + (size_t)z * N * M;
        #pragma unroll
        for (int i = 0; i < 2; ++i)
            #pragma unroll
            for (int r = 0; r < 4; ++r) {
                int o = oBase + wo + i * 16 + quad * 4 + r;
                #pragma unroll
                for (int j = 0; j < 2; ++j) {
                    int m = mBase + wm + j * 16 + lr;
                    pp[(size_t)o * M + m] = acc[i][j][r];
                }
            }
    }
}

// blocks: s2 [0,512) (split1, fused silu)  s4 [512,1536) (split4)  s8 [1536,2560) (split8)
__global__ __launch_bounds__(256) void gemm_all(
    const unsigned short* __restrict__ w2b, const unsigned short* __restrict__ w4b,
    const unsigned short* __restrict__ w8b,
    const unsigned short* __restrict__ v2, const unsigned short* __restrict__ v4,
    const unsigned short* __restrict__ v8,
    const float* __restrict__ b2, float* __restrict__ bev2,
    float* __restrict__ part4, float* __restrict__ part8)
{
    __shared__ __align__(16) unsigned short As[2][64 * 72];
    __shared__ __align__(16) unsigned short Bs[2][64 * 72];
    int bid = blockIdx.x;
    int tid = threadIdx.x;
    if (bid < 512)          // s2: M=4096(64 tiles,log6), N=256(4,log2), z=2
        gemm_tile(w2b, v2, b2, bev2, nullptr, 256, 1024, 4096, 1, bid, 6, 2, tid, As, Bs);
    else if (bid < 1536)    // s4: M=1024(16,log4), N=512(8,log3), z=8
        gemm_tile(w4b, v4, nullptr, nullptr, part4, 512, 2048, 1024, 4, bid - 512, 4, 3, tid, As, Bs);
    else                    // s8: M=256(4,log2), N=1024(16,log4), z=16
        gemm_tile(w8b, v8, nullptr, nullptr, part8, 1024, 4096, 256, 8, bid - 1536, 2, 4, tid, As, Bs);
}

// ===================== PHASE 5: reduce + bias + silu + mask =================
__device__ __forceinline__ void reduce_seg(
    const float* __restrict__ partial, const float* __restrict__ bias,
    float* __restrict__ out, int N, int M, int kSplit, size_t idx)
{
    int m4 = M >> 2;
    int mi = (int)(idx % m4);
    int o  = (int)((idx / m4) % N);
    int b  = (int)(idx / ((size_t)m4 * N));
    size_t base = ((size_t)b * N + o) * M + (size_t)mi * 4;
    size_t stride = (size_t)2 * N * M;
    float4 s = *reinterpret_cast<const float4*>(partial + base);
    for (int k = 1; k < kSplit; ++k) {
        float4 t = *reinterpret_cast<const float4*>(partial + base + (size_t)k * stride);
        s.x += t.x; s.y += t.y; s.z += t.z; s.w += t.w;
    }
    float bi = bias[o];
    float xs[4] = {s.x + bi, s.y + bi, s.z + bi, s.w + bi};
    float4 r;
    r.x = xs[0] / (1.f + __expf(-xs[0]));
    r.y = xs[1] / (1.f + __expf(-xs[1]));
    r.z = xs[2] / (1.f + __expf(-xs[2]));
    r.w = xs[3] / (1.f + __expf(-xs[3]));
    *reinterpret_cast<float4*>(out + base) = r;
}

// blocks: s4 reduce [0,1024)  s8 reduce [1024,1536)  mask [1536,1664)
__global__ __launch_bounds__(256) void reduce_mask_all(
    const float* __restrict__ part4, const float* __restrict__ b4, float* __restrict__ bev4,
    const float* __restrict__ part8, const float* __restrict__ b8, float* __restrict__ bev8,
    const float* __restrict__ c2, float* __restrict__ mask)
{
    int bid = blockIdx.x;
    int tid = threadIdx.x;
    if (bid < 1024) {
        reduce_seg(part4, b4, bev4, 512, 1024, 4, (size_t)bid * 256 + tid);
    } else if (bid < 1536) {
        reduce_seg(part8, b8, bev8, 1024, 256, 8, (size_t)(bid - 1024) * 256 + tid);
    } else {
        int idx = (bid - 1536) * 256 + tid;          // [0, 32768)
        int n = idx & 16383;
        int b = idx >> 14;
        float best = 0.f;
        #pragma unroll
        for (int s = 0; s < S_; ++s) {
            float2 g = ((const float2*)c2)[(size_t)(b * S_ + s) * 16384 + n];
            bool valid = (g.x >= -1.f) && (g.x <= 1.f) && (g.y >= -1.f) && (g.y <= 1.f);
            if (valid) best = 1.f;
        }
        mask[idx] = best;
    }
}

} // namespace

extern "C" void kernel_launch(void* const* d_in, const int* in_sizes, int n_in,
                              void* d_out, int out_size, void* d_ws, size_t ws_size,
                              hipStream_t stream)
{
    const float* x3 = (const float*)d_in[0];
    const float* x4 = (const float*)d_in[1];
    const float* x5 = (const float*)d_in[2];
    const float* c2 = (const float*)d_in[3];
    const float* c4 = (const float*)d_in[4];
    const float* c8 = (const float*)d_in[5];
    const float* w2 = (const float*)d_in[6];
    const float* b2 = (const float*)d_in[7];
    const float* w4 = (const float*)d_in[8];
    const float* b4 = (const float*)d_in[9];
    const float* w8 = (const float*)d_in[10];
    const float* b8 = (const float*)d_in[11];

    float* out  = (float*)d_out;
    float* bev2 = out;
    float* bev4 = bev2 + (long)2 * 256 * 64 * 64;
    float* bev8 = bev4 + (long)2 * 512 * 32 * 32;
    float* mask = bev8 + (long)2 * 1024 * 16 * 16;

    // ws layout (MiB offsets; ws_size = 256 MiB per round-5 WRITE_SIZE evidence):
    //   featT2 0(16)  featT4 16(8)  featT8 24(4)
    //   V2 28(16)     V4 44(8)      V8 52(4)
    //   w2bf 56(0.5)  w4bf 57(2)    w8bf 59(8)
    //   part4 68(16)  part8 84(16)  -> end 100 MiB
    char* ws = (char*)d_ws;
    unsigned short* f2v  = (unsigned short*)(ws);
    unsigned short* f4v  = (unsigned short*)(ws + (16L << 20));
    unsigned short* f8v  = (unsigned short*)(ws + (24L << 20));
    unsigned short* v2v  = (unsigned short*)(ws + (28L << 20));
    unsigned short* v4v  = (unsigned short*)(ws + (44L << 20));
    unsigned short* v8v  = (unsigned short*)(ws + (52L << 20));
    unsigned short* w2bf = (unsigned short*)(ws + (56L << 20));
    unsigned short* w4bf = (unsigned short*)(ws + (57L << 20));
    unsigned short* w8bf = (unsigned short*)(ws + (59L << 20));
    float*          part4 = (float*)(ws + (68L << 20));
    float*          part8 = (float*)(ws + (84L << 20));

    transpose_all<<<dim3(14336), 256, 0, stream>>>(x3, x4, x5, f2v, f4v, f8v);
    cvt_w_all<<<dim3(5376), 256, 0, stream>>>(w2, w4, w8, w2bf, w4bf, w8bf);
    sample_all<<<dim3(3584), 256, 0, stream>>>(f2v, f4v, f8v, c2, c4, c8, v2v, v4v, v8v);
    gemm_all<<<dim3(2560), 256, 0, stream>>>(w2bf, w4bf, w8bf, v2v, v4v, v8v,
                                             b2, bev2, part4, part8);
    reduce_mask_all<<<dim3(1664), 256, 0, stream>>>(part4, b4, bev4, part8, b8, bev8,
                                                    c2, mask);
}